// Round 11
// baseline (162.504 us; speedup 1.0000x reference)
//
#include <hip/hip_runtime.h>
#include <math.h>

#define NB 16
#define NS 48
#define NL 64
#define NQ 32
#define NE 300
#define NF 256
#define KP 320
#define QROWS 36

typedef __attribute__((ext_vector_type(8))) short short8;
typedef __attribute__((ext_vector_type(4))) float f32x4;

#define MFMA(a,b,c) __builtin_amdgcn_mfma_f32_16x16x32_bf16((a),(b),(c),0,0,0)

__device__ __forceinline__ unsigned short f2bf(float f) {
    unsigned u = __float_as_uint(f);
    u += 0x7fff + ((u >> 16) & 1);           // RNE
    return (unsigned short)(u >> 16);
}

__device__ __forceinline__ float wave_reduce_sum(float v) {
#pragma unroll
    for (int off = 32; off; off >>= 1) v += __shfl_xor(v, off, 64);
    return v;
}

// four independent top-5 pools, interleaved for ILP
__device__ __forceinline__ void top5_pool4(float v0, float v1, float v2, float v3,
                                           int lane, float* mx, float* mn) {
    float s0 = 0.f, s1 = 0.f, s2 = 0.f, s3 = 0.f;
    float x0 = 0.f, x1 = 0.f, x2 = 0.f, x3 = 0.f;
#pragma unroll
    for (int i = 0; i < 5; ++i) {
        float m0 = v0, m1 = v1, m2 = v2, m3 = v3;
#pragma unroll
        for (int off = 32; off; off >>= 1) {
            m0 = fmaxf(m0, __shfl_xor(m0, off, 64));
            m1 = fmaxf(m1, __shfl_xor(m1, off, 64));
            m2 = fmaxf(m2, __shfl_xor(m2, off, 64));
            m3 = fmaxf(m3, __shfl_xor(m3, off, 64));
        }
        if (i == 0) { x0 = m0; x1 = m1; x2 = m2; x3 = m3; }
        s0 += m0; s1 += m1; s2 += m2; s3 += m3;
        unsigned long long k0 = __ballot(v0 == m0);
        unsigned long long k1 = __ballot(v1 == m1);
        unsigned long long k2 = __ballot(v2 == m2);
        unsigned long long k3 = __ballot(v3 == m3);
        if (lane == __ffsll(k0) - 1) v0 = -3.4e38f;
        if (lane == __ffsll(k1) - 1) v1 = -3.4e38f;
        if (lane == __ffsll(k2) - 1) v2 = -3.4e38f;
        if (lane == __ffsll(k3) - 1) v3 = -3.4e38f;
    }
    mx[0] = x0; mx[1] = x1; mx[2] = x2; mx[3] = x3;
    mn[0] = s0 * 0.2f; mn[1] = s1 * 0.2f; mn[2] = s2 * 0.2f; mn[3] = s3 * 0.2f;
}

// ---------- pack conv_w into MFMA B-fragment order; zero qcssq + sent_ws + ctr
__global__ void wb2_kernel(const float* __restrict__ conv_w, short8* __restrict__ Wb2,
                           unsigned int* __restrict__ done_ctr,
                           float* __restrict__ qcssq, float* __restrict__ sent_ws) {
    if (blockIdx.x == 0 && threadIdx.x == 0) done_ctr[0] = 0u;
    int i = blockIdx.x * 256 + threadIdx.x;
    if (i < NB * NQ) qcssq[i] = 0.f;
    if (i < NB * NS) sent_ws[i] = 0.f;
    if (i >= 120 * 256) return;
    int rl = i & 15;
    int ftile = (i >> 4) & 15;
    int c = i >> 8;
    int kg = c & 3, rest = c >> 2;
    int ks = rest % 10, j = rest / 10;
    int f = ftile * 16 + rl;
    int k0 = ks * 32 + kg * 8;
    const float* src = conv_w + (size_t)(f * 3 + j) * NE;
    short8 h;
#pragma unroll
    for (int e = 0; e < 8; ++e) {
        int k = k0 + e;
        h[e] = (short)((k < NE) ? f2bf(src[k]) : (unsigned short)0);
    }
    Wb2[i] = h;
}

// ---------- q_emb gather -> taps layout + A-fragments + fp32 q_norm
__global__ void qe_kernel(const int* __restrict__ question, const float* __restrict__ embeds,
                          unsigned short* __restrict__ qe, short8* __restrict__ qef,
                          float* __restrict__ q_norm) {
    int row = blockIdx.x;                        // b*36 + r
    int b = row / QROWS, r = row % QROWS;
    int l = threadIdx.x;
    unsigned short* dst = qe + (size_t)row * KP;
    if (r < NQ) {
        int tok = question[b * NQ + r];
        const float4* rp = (const float4*)(embeds + (size_t)tok * NE);
        short8 h = {0, 0, 0, 0, 0, 0, 0, 0};
        float ss = 0.f;
        if (l < 38) {
            float4 v0 = rp[2 * l];
            ss += v0.x * v0.x + v0.y * v0.y + v0.z * v0.z + v0.w * v0.w;
            h[0] = (short)f2bf(v0.x); h[1] = (short)f2bf(v0.y);
            h[2] = (short)f2bf(v0.z); h[3] = (short)f2bf(v0.w);
            if (2 * l + 1 < 75) {
                float4 v1 = rp[2 * l + 1];
                ss += v1.x * v1.x + v1.y * v1.y + v1.z * v1.z + v1.w * v1.w;
                h[4] = (short)f2bf(v1.x); h[5] = (short)f2bf(v1.y);
                h[6] = (short)f2bf(v1.z); h[7] = (short)f2bf(v1.w);
            }
        }
        if (l < 40) {
            *(short8*)(dst + 8 * l) = h;
            qef[((size_t)(b * 2 + (r >> 4)) * 40 + l) * 16 + (r & 15)] = h;
        }
        ss = wave_reduce_sum(ss);
        if (l == 0) q_norm[b * NQ + r] = sqrtf(ss);
    } else {
        if (l < 40) {
            short8 z = {0, 0, 0, 0, 0, 0, 0, 0};
            *(short8*)(dst + 8 * l) = z;
        }
    }
}

// ---------- q_conv via MFMA -> A-fragments + partial qc ssq
__global__ __launch_bounds__(256) void qconv_mfma_kernel(
        const unsigned short* __restrict__ qe, const short8* __restrict__ Wb2,
        short8* __restrict__ qcf, float* __restrict__ qcssq) {
    __shared__ unsigned short tile[NQ][72];
    int b = blockIdx.x >> 2, fq = blockIdx.x & 3;
    int tid = threadIdx.x, lane = tid & 63, w = tid >> 6;
    int rl = lane & 15, kg = lane >> 4;
    int ftile = fq * 4 + w;
    f32x4 acc0 = (f32x4){0.f, 0.f, 0.f, 0.f};
    f32x4 acc1 = (f32x4){0.f, 0.f, 0.f, 0.f};
    for (int j = 0; j < 3; ++j) {
#pragma unroll 2
        for (int ks = 0; ks < 10; ++ks) {
            int k = ks * 32 + kg * 8;
            int c = (j * 10 + ks) * 4 + kg;
            short8 a0 = *(const short8*)(qe + ((size_t)(b * QROWS) + rl + j) * KP + k);
            short8 a1 = *(const short8*)(qe + ((size_t)(b * QROWS) + 16 + rl + j) * KP + k);
            short8 bb = Wb2[(c * 16 + ftile) * 16 + rl];
            acc0 = MFMA(a0, bb, acc0);
            acc1 = MFMA(a1, bb, acc1);
        }
    }
    int fl = w * 16 + rl;
#pragma unroll
    for (int reg = 0; reg < 4; ++reg) {
        tile[kg * 4 + reg][fl] = f2bf(acc0[reg]);
        tile[16 + kg * 4 + reg][fl] = f2bf(acc1[reg]);
    }
    __syncthreads();
    {
        int mh = tid >> 7, c_local = (tid >> 4) & 7, rl2 = tid & 15;
        short8 h = *(const short8*)(&tile[mh * 16 + rl2][c_local * 8]);
        qcf[((size_t)(b * 2 + mh) * 32 + 8 * fq + c_local) * 16 + rl2] = h;
    }
    {
        int qq = tid >> 3, fgrp = tid & 7;
        short8 h = *(const short8*)(&tile[qq][fgrp * 8]);
        float ss = 0.f;
#pragma unroll
        for (int e = 0; e < 8; ++e) {
            float v = __uint_as_float(((unsigned)(unsigned short)h[e]) << 16);
            ss += v * v;
        }
        ss += __shfl_xor(ss, 1, 64);
        ss += __shfl_xor(ss, 2, 64);
        ss += __shfl_xor(ss, 4, 64);
        if (fgrp == 0) atomicAdd(&qcssq[b * NQ + qq], ss);
    }
}

// ---------- K_pack: s_emb gather -> sB fragments + fp32 snorm; zero scssq
__global__ __launch_bounds__(256) void pack_kernel(
        const int* __restrict__ sentences, const float* __restrict__ embeds,
        short8* __restrict__ sB, float* __restrict__ snorm_g,
        float* __restrict__ scssq) {
    __shared__ unsigned short stg[16][328];
    __shared__ int toks[NL];
    int bs = blockIdx.x;
    int tid = threadIdx.x, lane = tid & 63, w = tid >> 6;
    if (tid < NL) {
        toks[tid] = sentences[(size_t)bs * NL + tid];
        scssq[bs * NL + tid] = 0.f;
    }
    __syncthreads();
    short8* sbb = sB + (size_t)bs * 40 * 64;
    for (int it = 0; it < 4; ++it) {
#pragma unroll
        for (int i = 0; i < 4; ++i) {
            int r16 = w * 4 + i;
            int r = it * 16 + r16;
            const float4* rp = (const float4*)(embeds + (size_t)toks[r] * NE);
            float ss;
            {
                float4 v = rp[lane];
                ss = v.x * v.x + v.y * v.y + v.z * v.z + v.w * v.w;
                ushort4 h = {f2bf(v.x), f2bf(v.y), f2bf(v.z), f2bf(v.w)};
                *(ushort4*)&stg[r16][4 * lane] = h;
            }
            if (lane < 11) {
                float4 v = rp[64 + lane];
                ss += v.x * v.x + v.y * v.y + v.z * v.z + v.w * v.w;
                ushort4 h = {f2bf(v.x), f2bf(v.y), f2bf(v.z), f2bf(v.w)};
                *(ushort4*)&stg[r16][256 + 4 * lane] = h;
            } else if (lane < 16) {
                ushort4 z = {0, 0, 0, 0};
                *(ushort4*)&stg[r16][256 + 4 * lane] = z;
            }
            ss = wave_reduce_sum(ss);
            if (lane == 0) snorm_g[bs * NL + r] = sqrtf(ss);
        }
        __syncthreads();
        {
            int c = tid >> 4, rl = tid & 15;
            for (; c < 40; c += 16) {
                short8 h = *(const short8*)&stg[rl][c * 8];
                sbb[(size_t)c * 64 + it * 16 + rl] = h;
            }
        }
        __syncthreads();
    }
}

// ---------- K_ins: split by q-half. block=(bs,qh). M=16 q, sim pools 4 q/wave.
__global__ __launch_bounds__(256) void ins_kernel(
        const int* __restrict__ sentences, const int* __restrict__ question,
        const short8* __restrict__ sB, const short8* __restrict__ qef,
        const float* __restrict__ snorm_g, const float* __restrict__ q_norm,
        float2* __restrict__ fpool_ins) {
    __shared__ float sim[16][66];
    __shared__ float qn_s[16], qmf_s[16];
    int bs = blockIdx.x >> 1, qh = blockIdx.x & 1;
    int b = bs / NS;
    int tid = threadIdx.x, lane = tid & 63, w = tid >> 6;
    int rl = lane & 15, kg = lane >> 4;
    int t = (w << 4) + rl;
    if (tid < 16) qn_s[tid] = q_norm[b * NQ + qh * 16 + tid];
    else if (tid < 32) {
        int q = tid - 16;
        qmf_s[q] = (question[b * NQ + qh * 16 + q] > 1) ? 1.f : 0.f;
    }
    float sn_t = snorm_g[bs * NL + t];
    float sm_t = (sentences[(size_t)bs * NL + t] > 1) ? 1.f : 0.f;
    __syncthreads();
    f32x4 i0 = (f32x4){0.f, 0.f, 0.f, 0.f};
    const short8* qf = qef + (size_t)((b * 2 + qh) * 40) * 16;
    const short8* sbb = sB + (size_t)bs * 40 * 64;
#pragma unroll 2
    for (int ks = 0; ks < 10; ++ks) {
        int c = ks * 4 + kg;
        short8 bB = sbb[(size_t)c * 64 + t];
        i0 = MFMA(qf[c * 16 + rl], bB, i0);
    }
    float inv_t = sm_t / sn_t;
#pragma unroll
    for (int reg = 0; reg < 4; ++reg) {
        int ql = kg * 4 + reg;
        sim[ql][t] = i0[reg] / qn_s[ql] * inv_t * qmf_s[ql];
    }
    __syncthreads();
    int ql0 = w << 2;
    float mx[4], mn[4];
    top5_pool4(sim[ql0 + 0][lane], sim[ql0 + 1][lane], sim[ql0 + 2][lane],
               sim[ql0 + 3][lane], lane, mx, mn);
    if (lane == 0)
#pragma unroll
        for (int p = 0; p < 4; ++p)
            fpool_ins[(size_t)bs * NQ + qh * 16 + ql0 + p] = (float2){mx[p], mn[p]};
}

// ---------- K_conv: split by f-half. block=(bs,fh). Wave owns 2 f-tiles (32 f).
__global__ __launch_bounds__(256) void conv_kernel(
        const short8* __restrict__ sB, const short8* __restrict__ Wb2,
        short8* __restrict__ scB, float* __restrict__ scssq) {
    __shared__ unsigned short scr[4][16][40];   // wave-private scratch, 5120 B
    int bs = blockIdx.x >> 1, fh = blockIdx.x & 1;
    int tid = threadIdx.x, lane = tid & 63, w = tid >> 6;
    int rl = lane & 15, kg = lane >> 4;
    const short8* sbb = sB + (size_t)bs * 40 * 64;

    f32x4 cacc[4][2];
#pragma unroll
    for (int m = 0; m < 4; ++m)
#pragma unroll
        for (int nn = 0; nn < 2; ++nn) cacc[m][nn] = (f32x4){0.f, 0.f, 0.f, 0.f};

    for (int j = 0; j < 3; ++j) {
#pragma unroll 2
        for (int ks = 0; ks < 10; ++ks) {
            int cA = ks * 4 + kg;
            int c = (j * 10 + ks) * 4 + kg;
            short8 a[4], bb[2];
#pragma unroll
            for (int m = 0; m < 3; ++m)
                a[m] = sbb[(size_t)cA * 64 + m * 16 + rl + j];
            {
                int row3 = 48 + rl + j;
                short8 z = {0, 0, 0, 0, 0, 0, 0, 0};
                a[3] = (row3 < 64) ? sbb[(size_t)cA * 64 + row3] : z;
            }
#pragma unroll
            for (int nn = 0; nn < 2; ++nn)
                bb[nn] = Wb2[(c * 16 + (fh * 8 + w * 2 + nn)) * 16 + rl];
#pragma unroll
            for (int m = 0; m < 4; ++m)
#pragma unroll
                for (int nn = 0; nn < 2; ++nn)
                    cacc[m][nn] = MFMA(a[m], bb[nn], cacc[m][nn]);
        }
    }

    short8* scb = scB + (size_t)bs * 32 * 64;
#pragma unroll
    for (int m = 0; m < 4; ++m) {
#pragma unroll
        for (int nn = 0; nn < 2; ++nn)
#pragma unroll
            for (int reg = 0; reg < 4; ++reg)
                scr[w][kg * 4 + reg][nn * 16 + rl] = f2bf(cacc[m][nn][reg]);
#pragma unroll
        for (int reg = 0; reg < 4; ++reg) {
            float ss = 0.f;
#pragma unroll
            for (int nn = 0; nn < 2; ++nn) {
                float v = cacc[m][nn][reg];
                ss += v * v;
            }
            ss += __shfl_xor(ss, 1, 64);
            ss += __shfl_xor(ss, 2, 64);
            ss += __shfl_xor(ss, 4, 64);
            ss += __shfl_xor(ss, 8, 64);
            if (rl == 0) atomicAdd(&scssq[bs * NL + m * 16 + kg * 4 + reg], ss);
        }
        {
            int cl = lane >> 4;                  // 0..3
            int rl2 = lane & 15;
            short8 v = *(const short8*)&scr[w][rl2][cl * 8];
            scb[(size_t)(fh * 16 + w * 4 + cl) * 64 + m * 16 + rl2] = v;
        }
    }
}

// ---------- K_sens: split by q-half. sens MFMA + pools + head; last block: loss.
__global__ __launch_bounds__(256) void sens_kernel(
        const float* __restrict__ sim_oh,
        const short8* __restrict__ scB, const short8* __restrict__ qcf,
        const float* __restrict__ qcssq, const float* __restrict__ scssq,
        const float2* __restrict__ fpool_ins,
        const float* __restrict__ lin_w, const float* __restrict__ lin_b,
        const int* __restrict__ tsent, const int* __restrict__ tdoc,
        unsigned int* __restrict__ done_ctr,
        float* __restrict__ sent_ws, float* __restrict__ d_out) {
    __shared__ float sim[16][66];
    __shared__ float qcn_s[16];
    __shared__ float wq[4];
    __shared__ int lastflag;
    __shared__ float red2[4];
    __shared__ float dred[NB];
    int bs = blockIdx.x >> 1, qh = blockIdx.x & 1;
    int b = bs / NS;
    int tid = threadIdx.x, lane = tid & 63, w = tid >> 6;
    int rl = lane & 15, kg = lane >> 4;
    int t = (w << 4) + rl;
    if (tid < 16) qcn_s[tid] = sqrtf(qcssq[b * NQ + qh * 16 + tid]);
    float scn_t = sqrtf(scssq[bs * NL + t]);
    float oh[4];
#pragma unroll
    for (int qi = 0; qi < 4; ++qi) {
        int q = qh * 16 + (w << 2) + qi;
        oh[qi] = sim_oh[((size_t)bs * NQ + q) * NL + lane];
    }
    f32x4 sacc0 = (f32x4){0.f, 0.f, 0.f, 0.f};
    const short8* qc = qcf + (size_t)((b * 2 + qh) * 32) * 16;
    const short8* scb = scB + (size_t)bs * 32 * 64;
#pragma unroll 2
    for (int ks = 0; ks < 8; ++ks) {
        int c = ks * 4 + kg;
        short8 bB = scb[(size_t)c * 64 + t];
        sacc0 = MFMA(qc[c * 16 + rl], bB, sacc0);
    }
    __syncthreads();            // qcn_s ready
    float inv_t = 1.f / scn_t;
#pragma unroll
    for (int reg = 0; reg < 4; ++reg) {
        int ql = kg * 4 + reg;
        sim[ql][t] = sacc0[reg] / qcn_s[ql] * inv_t;
    }
    __syncthreads();

    {
        float lw0 = lin_w[0], lw1 = lin_w[1], lw2 = lin_w[2];
        float lw3 = lin_w[3], lw4 = lin_w[4], lw5 = lin_w[5];
        float lb = lin_b[0];
        int ql0 = w << 2;
        float mxs[4], mns[4], mxo[4], mno[4];
        top5_pool4(sim[ql0 + 0][lane], sim[ql0 + 1][lane], sim[ql0 + 2][lane],
                   sim[ql0 + 3][lane], lane, mxs, mns);
        top5_pool4(oh[0], oh[1], oh[2], oh[3], lane, mxo, mno);
        float psum = 0.f;
#pragma unroll
        for (int qi = 0; qi < 4; ++qi) {
            float2 fp = fpool_ins[(size_t)bs * NQ + qh * 16 + ql0 + qi];
            float z = fp.x * lw0 + fp.y * lw1 + mxs[qi] * lw2 + mns[qi] * lw3 +
                      mxo[qi] * lw4 + mno[qi] * lw5 + lb;
            psum += 1.f / (1.f + expf(-z));
        }
        if (lane == 0) wq[w] = psum;
    }
    __syncthreads();
    if (tid == 0) {
        float partial = (wq[0] + wq[1] + wq[2] + wq[3]) * (1.f / 32.f);
        atomicAdd(&sent_ws[bs], partial);
        unsigned old = __hip_atomic_fetch_add(done_ctr, 1u, __ATOMIC_ACQ_REL,
                                              __HIP_MEMORY_SCOPE_AGENT);
        lastflag = (old == (unsigned)(2 * NB * NS - 1)) ? 1 : 0;
    }
    __syncthreads();

    if (lastflag) {
        float acc_l = 0.f;
        for (int i = tid; i < NB * NS; i += 256) {
            float p = __hip_atomic_load(&sent_ws[i], __ATOMIC_ACQUIRE, __HIP_MEMORY_SCOPE_AGENT);
            d_out[1 + i] = p;
            float tt2 = (float)tsent[i];
            acc_l += tt2 * logf(p) + (1.f - tt2) * logf(1.f - p);
        }
        acc_l = wave_reduce_sum(acc_l);
        if ((tid & 63) == 0) red2[tid >> 6] = acc_l;
        if (tid < NB) {
            float m = -3.4e38f;
            for (int s = 0; s < NS; ++s)
                m = fmaxf(m, __hip_atomic_load(&sent_ws[tid * NS + s], __ATOMIC_ACQUIRE,
                                               __HIP_MEMORY_SCOPE_AGENT));
            d_out[1 + NB * NS + tid] = m;
            float tt2 = (float)tdoc[tid];
            dred[tid] = tt2 * logf(m) + (1.f - tt2) * logf(1.f - m);
        }
        __syncthreads();
        if (tid == 0) {
            float sal = -(red2[0] + red2[1] + red2[2] + red2[3]) / (float)(NB * NS);
            float dsum = 0.f;
            for (int i = 0; i < NB; ++i) dsum += dred[i];
            float dal = -dsum / (float)NB;
            d_out[0] = 0.5f * (sal + dal);
        }
    }
}

extern "C" void kernel_launch(void* const* d_in, const int* in_sizes, int n_in,
                              void* d_out, int out_size, void* d_ws, size_t ws_size,
                              hipStream_t stream) {
    const int* sentences = (const int*)d_in[0];
    const int* question = (const int*)d_in[1];
    const int* tsent = (const int*)d_in[2];
    const int* tdoc = (const int*)d_in[3];
    const float* sim_oh = (const float*)d_in[4];
    const float* embeds = (const float*)d_in[5];
    const float* conv_w = (const float*)d_in[6];
    const float* lin_w = (const float*)d_in[7];
    const float* lin_b = (const float*)d_in[8];
    float* out = (float*)d_out;

    char* wsc = (char*)d_ws;
    short8* Wb2            = (short8*)(wsc);                     // 491520 B
    unsigned short* qe_old = (unsigned short*)(wsc + 491520);    // 368640 B
    short8* qef            = (short8*)(wsc + 860160);            // 327680 B
    short8* qcf            = (short8*)(wsc + 1187840);           // 262144 B
    float* q_norm          = (float*)(wsc + 1449984);            // 2048 B
    float* qcssq           = (float*)(wsc + 1452032);            // 2048 B
    float* sent_ws         = (float*)(wsc + 1454080);            // 3072 B
    unsigned int* done_ctr = (unsigned int*)(wsc + 1457152);     // 16 B
    float* snorm_g         = (float*)(wsc + 1457168);            // 196608 B
    float* scssq           = (float*)(wsc + 1653776);            // 196608 B
    float2* fpool_ins      = (float2*)(wsc + 1850384);           // 196608 B
    short8* sB             = (short8*)(wsc + 2046992);           // 31457280 B
    short8* scB            = (short8*)(wsc + 33504272);          // 25165824 B

    wb2_kernel<<<120, 256, 0, stream>>>(conv_w, Wb2, done_ctr, qcssq, sent_ws);
    qe_kernel<<<NB * QROWS, 64, 0, stream>>>(question, embeds, qe_old, qef, q_norm);
    qconv_mfma_kernel<<<NB * 4, 256, 0, stream>>>(qe_old, Wb2, qcf, qcssq);
    pack_kernel<<<NB * NS, 256, 0, stream>>>(sentences, embeds, sB, snorm_g, scssq);
    ins_kernel<<<NB * NS * 2, 256, 0, stream>>>(sentences, question, sB, qef,
                                                snorm_g, q_norm, fpool_ins);
    conv_kernel<<<NB * NS * 2, 256, 0, stream>>>(sB, Wb2, scB, scssq);
    sens_kernel<<<NB * NS * 2, 256, 0, stream>>>(
        sim_oh, scB, qcf, qcssq, scssq, fpool_ins,
        lin_w, lin_b, tsent, tdoc, done_ctr, sent_ws, out);
}

// Round 12
// 126.235 us; speedup vs baseline: 1.2873x; 1.2873x over previous
//
#include <hip/hip_runtime.h>
#include <math.h>

#define NB 16
#define NS 48
#define NL 64
#define NQ 32
#define NE 300
#define NF 256
#define KP 320            // padded K for embeddings (bf16)
#define QROWS 36          // qe rows per b (32 + zero pad for taps)

typedef __attribute__((ext_vector_type(8))) short short8;
typedef __attribute__((ext_vector_type(4))) float f32x4;

#define MFMA(a,b,c) __builtin_amdgcn_mfma_f32_16x16x32_bf16((a),(b),(c),0,0,0)

__device__ __forceinline__ unsigned short f2bf(float f) {
    unsigned u = __float_as_uint(f);
    u += 0x7fff + ((u >> 16) & 1);           // RNE
    return (unsigned short)(u >> 16);
}

// dynamic-LDS byte offsets (s_conv region overlays s_emb region)
#define SE_PITCH 640                        // 320 bf16 per row, 66 rows
#define SC_PITCH 512                        // 256 bf16 per row, 64 rows (overlay)
#define SIM_OFF (66 * 640)                  // 42240
#define SIM_PITCH 66                        // floats per q-row
#define DYN_LDS (SIM_OFF + NQ * SIM_PITCH * 4)   // 50688 bytes

__device__ __forceinline__ float wave_reduce_sum(float v) {
#pragma unroll
    for (int off = 32; off; off >>= 1) v += __shfl_xor(v, off, 64);
    return v;
}

// four independent top-5 pools, interleaved for ILP
__device__ __forceinline__ void top5_pool4(float v0, float v1, float v2, float v3,
                                           int lane, float* mx, float* mn) {
    float s0 = 0.f, s1 = 0.f, s2 = 0.f, s3 = 0.f;
    float x0 = 0.f, x1 = 0.f, x2 = 0.f, x3 = 0.f;
#pragma unroll
    for (int i = 0; i < 5; ++i) {
        float m0 = v0, m1 = v1, m2 = v2, m3 = v3;
#pragma unroll
        for (int off = 32; off; off >>= 1) {
            m0 = fmaxf(m0, __shfl_xor(m0, off, 64));
            m1 = fmaxf(m1, __shfl_xor(m1, off, 64));
            m2 = fmaxf(m2, __shfl_xor(m2, off, 64));
            m3 = fmaxf(m3, __shfl_xor(m3, off, 64));
        }
        if (i == 0) { x0 = m0; x1 = m1; x2 = m2; x3 = m3; }
        s0 += m0; s1 += m1; s2 += m2; s3 += m3;
        unsigned long long k0 = __ballot(v0 == m0);
        unsigned long long k1 = __ballot(v1 == m1);
        unsigned long long k2 = __ballot(v2 == m2);
        unsigned long long k3 = __ballot(v3 == m3);
        if (lane == __ffsll(k0) - 1) v0 = -3.4e38f;
        if (lane == __ffsll(k1) - 1) v1 = -3.4e38f;
        if (lane == __ffsll(k2) - 1) v2 = -3.4e38f;
        if (lane == __ffsll(k3) - 1) v3 = -3.4e38f;
    }
    mx[0] = x0; mx[1] = x1; mx[2] = x2; mx[3] = x3;
    mn[0] = s0 * 0.2f; mn[1] = s1 * 0.2f; mn[2] = s2 * 0.2f; mn[3] = s3 * 0.2f;
}

// ---------- prep: blocks 0..119 pack conv_w -> Wb2 fragments (+zero qcssq/ctr);
//            blocks 120..263 gather q_emb (4 rows each) -> qe taps + qef fragments + q_norm
__global__ __launch_bounds__(256) void prep_kernel(
        const float* __restrict__ conv_w, const int* __restrict__ question,
        const float* __restrict__ embeds,
        short8* __restrict__ Wb2, unsigned short* __restrict__ qe,
        short8* __restrict__ qef, float* __restrict__ q_norm,
        float* __restrict__ qcssq, unsigned int* __restrict__ done_ctr) {
    int blk = blockIdx.x;
    int tid = threadIdx.x;
    if (blk < 120) {
        if (blk == 0 && tid == 0) done_ctr[0] = 0u;
        int i = blk * 256 + tid;
        if (i < NB * NQ) qcssq[i] = 0.f;
        int rl = i & 15;
        int ftile = (i >> 4) & 15;
        int c = i >> 8;
        int kg = c & 3, rest = c >> 2;
        int ks = rest % 10, j = rest / 10;
        int f = ftile * 16 + rl;
        int k0 = ks * 32 + kg * 8;
        const float* src = conv_w + (size_t)(f * 3 + j) * NE;
        short8 h;
#pragma unroll
        for (int e = 0; e < 8; ++e) {
            int k = k0 + e;
            h[e] = (short)((k < NE) ? f2bf(src[k]) : (unsigned short)0);
        }
        Wb2[i] = h;
    } else {
        int row = (blk - 120) * 4 + (tid >> 6);  // 0..575 = b*36 + r
        int b = row / QROWS, r = row % QROWS;
        int l = tid & 63;
        unsigned short* dst = qe + (size_t)row * KP;
        if (r < NQ) {
            int tok = question[b * NQ + r];
            const float4* rp = (const float4*)(embeds + (size_t)tok * NE);
            short8 h = {0, 0, 0, 0, 0, 0, 0, 0};
            float ss = 0.f;
            if (l < 38) {
                float4 v0 = rp[2 * l];
                ss += v0.x * v0.x + v0.y * v0.y + v0.z * v0.z + v0.w * v0.w;
                h[0] = (short)f2bf(v0.x); h[1] = (short)f2bf(v0.y);
                h[2] = (short)f2bf(v0.z); h[3] = (short)f2bf(v0.w);
                if (2 * l + 1 < 75) {
                    float4 v1 = rp[2 * l + 1];
                    ss += v1.x * v1.x + v1.y * v1.y + v1.z * v1.z + v1.w * v1.w;
                    h[4] = (short)f2bf(v1.x); h[5] = (short)f2bf(v1.y);
                    h[6] = (short)f2bf(v1.z); h[7] = (short)f2bf(v1.w);
                }
            }
            if (l < 40) {
                *(short8*)(dst + 8 * l) = h;
                qef[((size_t)(b * 2 + (r >> 4)) * 40 + l) * 16 + (r & 15)] = h;
            }
            ss = wave_reduce_sum(ss);
            if (l == 0) q_norm[b * NQ + r] = sqrtf(ss);
        } else {
            if (l < 40) {
                short8 z = {0, 0, 0, 0, 0, 0, 0, 0};
                *(short8*)(dst + 8 * l) = z;
            }
        }
    }
}

// ---------- q_conv via MFMA -> A-fragments + partial qc ssq (certified r9)
__global__ __launch_bounds__(256) void qconv_mfma_kernel(
        const unsigned short* __restrict__ qe, const short8* __restrict__ Wb2,
        short8* __restrict__ qcf, float* __restrict__ qcssq) {
    __shared__ unsigned short tile[NQ][72];
    int b = blockIdx.x >> 2, fq = blockIdx.x & 3;
    int tid = threadIdx.x, lane = tid & 63, w = tid >> 6;
    int rl = lane & 15, kg = lane >> 4;
    int ftile = fq * 4 + w;
    f32x4 acc0 = (f32x4){0.f, 0.f, 0.f, 0.f};
    f32x4 acc1 = (f32x4){0.f, 0.f, 0.f, 0.f};
    for (int j = 0; j < 3; ++j) {
#pragma unroll 2
        for (int ks = 0; ks < 10; ++ks) {
            int k = ks * 32 + kg * 8;
            int c = (j * 10 + ks) * 4 + kg;
            short8 a0 = *(const short8*)(qe + ((size_t)(b * QROWS) + rl + j) * KP + k);
            short8 a1 = *(const short8*)(qe + ((size_t)(b * QROWS) + 16 + rl + j) * KP + k);
            short8 bb = Wb2[(c * 16 + ftile) * 16 + rl];
            acc0 = MFMA(a0, bb, acc0);
            acc1 = MFMA(a1, bb, acc1);
        }
    }
    int fl = w * 16 + rl;
#pragma unroll
    for (int reg = 0; reg < 4; ++reg) {
        tile[kg * 4 + reg][fl] = f2bf(acc0[reg]);
        tile[16 + kg * 4 + reg][fl] = f2bf(acc1[reg]);
    }
    __syncthreads();
    {
        int mh = tid >> 7, c_local = (tid >> 4) & 7, rl2 = tid & 15;
        short8 h = *(const short8*)(&tile[mh * 16 + rl2][c_local * 8]);
        qcf[((size_t)(b * 2 + mh) * 32 + 8 * fq + c_local) * 16 + rl2] = h;
    }
    {
        int qq = tid >> 3, fgrp = tid & 7;
        short8 h = *(const short8*)(&tile[qq][fgrp * 8]);
        float ss = 0.f;
#pragma unroll
        for (int e = 0; e < 8; ++e) {
            float v = __uint_as_float(((unsigned)(unsigned short)h[e]) << 16);
            ss += v * v;
        }
        ss += __shfl_xor(ss, 1, 64);
        ss += __shfl_xor(ss, 2, 64);
        ss += __shfl_xor(ss, 4, 64);
        if (fgrp == 0) atomicAdd(&qcssq[b * NQ + qq], ss);
    }
}

// ---------- fused per-(b,s), 4 waves (r6 structure + oh-prefetch + unrolled gather)
extern __shared__ char ldsc[];
__global__ __launch_bounds__(256, 3) void fused8_kernel(
    const int* __restrict__ sentences, const int* __restrict__ question,
    const float* __restrict__ sim_oh, const float* __restrict__ embeds,
    const short8* __restrict__ Wb2,
    const short8* __restrict__ qef, const short8* __restrict__ qcf,
    const float* __restrict__ q_norm, const float* __restrict__ qcssq,
    const float* __restrict__ lin_w, const float* __restrict__ lin_b,
    const int* __restrict__ tsent, const int* __restrict__ tdoc,
    unsigned int* __restrict__ done_ctr,
    float* __restrict__ sent_ws, float* __restrict__ d_out)
{
    __shared__ int toks[NL];
    __shared__ float smaskf[NL], snorm[NL], scnorm[NL];
    __shared__ float qn_s[NQ], qcn_s[NQ], qmf_s[NQ];
    __shared__ float wq[4];
    __shared__ float fpool[NQ][2];
    __shared__ int lastflag;
    __shared__ float red2[4];
    __shared__ float dred[NB];

    int tid = threadIdx.x, lane = tid & 63, w = tid >> 6;
    int rl = lane & 15, kg = lane >> 4;
    int bs = blockIdx.x, b = bs / NS;
    int t = (w << 4) + rl, t7 = t & 7;

    // ---- Phase 0: prefetch oh (independent HBM loads, hide under phases 1-6)
    float oh[8];
#pragma unroll
    for (int qi = 0; qi < 8; ++qi) {
        int q = (w << 3) + qi;
        oh[qi] = sim_oh[((size_t)bs * NQ + q) * NL + lane];
    }

    // ---- header loads
    if (tid < NL) {
        int tk = sentences[(size_t)bs * NL + tid];
        toks[tid] = tk;
        smaskf[tid] = (tk > 1) ? 1.f : 0.f;
    } else if (tid < NL + NQ) {
        int q = tid - NL;
        qn_s[q] = q_norm[b * NQ + q];
    } else if (tid < NL + 2 * NQ) {
        int q = tid - NL - NQ;
        qcn_s[q] = sqrtf(qcssq[b * NQ + q]);
    } else if (tid < NL + 3 * NQ) {
        int q = tid - NL - 2 * NQ;
        qmf_s[q] = (question[b * NQ + q] > 1) ? 1.f : 0.f;
    }
    __syncthreads();

    // ---- Phase 1: gather s_emb -> LDS bf16 (16B-granule XOR swizzle), stores only.
    //      Uniform 16 iterations (rows 0..63), unroll 4 for load ILP; tail rows 64,65 zeroed.
#pragma unroll 4
    for (int i = 0; i < 16; ++i) {
        int r = (i << 2) + w;
        char* rowbase = ldsc + r * SE_PITCH;
        int m7 = r & 7;
        const float4* rp = (const float4*)(embeds + (size_t)toks[r] * NE);
        {
            float4 v = rp[lane];
            ushort4 h = {f2bf(v.x), f2bf(v.y), f2bf(v.z), f2bf(v.w)};
            *(ushort4*)(rowbase + (((lane >> 1) ^ m7) << 4) + ((lane & 1) << 3)) = h;
        }
        if (lane < 11) {
            float4 v = rp[64 + lane];
            ushort4 h = {f2bf(v.x), f2bf(v.y), f2bf(v.z), f2bf(v.w)};
            int g = 64 + lane;
            *(ushort4*)(rowbase + (((g >> 1) ^ m7) << 4) + ((g & 1) << 3)) = h;
        }
        if (lane < 5) {
            int pk = 37 + ((lane + 1) >> 1);
            int sub = ((lane + 1) & 1) << 3;
            *(unsigned long long*)(rowbase + ((pk ^ m7) << 4) + sub) = 0ull;
        }
    }
    if (w < 2) {
        int r = 64 + w;
        if (lane < 40) {
            uint4 z = {0, 0, 0, 0};
            *(uint4*)(ldsc + r * SE_PITCH + (lane << 4)) = z;
        }
    }
    __syncthreads();

    // ---- Phase 2: sim_ins MFMA (wave w = t-tile, M=32 q) + snorm via Gram diag
    {
        f32x4 iacc0 = (f32x4){0.f, 0.f, 0.f, 0.f};
        f32x4 iacc1 = (f32x4){0.f, 0.f, 0.f, 0.f};
        f32x4 nB = (f32x4){0.f, 0.f, 0.f, 0.f};
        const short8* qf = qef + (size_t)(b * 80) * 16;
#pragma unroll 2
        for (int ks = 0; ks < 10; ++ks) {
            int c = ks * 4 + kg;
            short8 bB = *(const short8*)(ldsc + t * SE_PITCH + ((c ^ t7) << 4));
            short8 a0 = qf[c * 16 + rl];
            short8 a1 = qf[(40 + c) * 16 + rl];
            iacc0 = MFMA(a0, bB, iacc0);
            iacc1 = MFMA(a1, bB, iacc1);
            nB = MFMA(bB, bB, nB);
        }
        if (kg == (rl >> 2)) snorm[t] = sqrtf(nB[rl & 3]);
        __syncthreads();

        // ---- Phase 3: scale + write sim_ins
        float inv_t = smaskf[t] / snorm[t];
#pragma unroll
        for (int reg = 0; reg < 4; ++reg) {
            int q0 = kg * 4 + reg;
            float s0 = iacc0[reg] / qn_s[q0] * inv_t * qmf_s[q0];
            *(float*)(ldsc + SIM_OFF + (q0 * SIM_PITCH + t) * 4) = s0;
            int q1 = 16 + kg * 4 + reg;
            float s1 = iacc1[reg] / qn_s[q1] * inv_t * qmf_s[q1];
            *(float*)(ldsc + SIM_OFF + (q1 * SIM_PITCH + t) * 4) = s1;
        }
    }
    __syncthreads();

    // ---- Phase 4: pool sim_ins (wave w owns q = 8w..8w+7), 4-way ILP
    {
        int q0 = w << 3;
        float v[8];
#pragma unroll
        for (int qi = 0; qi < 8; ++qi)
            v[qi] = *(float*)(ldsc + SIM_OFF + ((q0 + qi) * SIM_PITCH + lane) * 4);
        float mx[4], mn[4];
        top5_pool4(v[0], v[1], v[2], v[3], lane, mx, mn);
        if (lane == 0)
#pragma unroll
            for (int p = 0; p < 4; ++p) { fpool[q0 + p][0] = mx[p]; fpool[q0 + p][1] = mn[p]; }
        top5_pool4(v[4], v[5], v[6], v[7], lane, mx, mn);
        if (lane == 0)
#pragma unroll
            for (int p = 0; p < 4; ++p) { fpool[q0 + 4 + p][0] = mx[p]; fpool[q0 + 4 + p][1] = mn[p]; }
    }

    // ---- Phase 5: conv MFMA. wave w owns f-tiles 4w..4w+3, all 4 t-tiles.
    f32x4 cacc[4][4];
#pragma unroll
    for (int m = 0; m < 4; ++m)
#pragma unroll
        for (int nn = 0; nn < 4; ++nn) cacc[m][nn] = (f32x4){0.f, 0.f, 0.f, 0.f};
    for (int j = 0; j < 3; ++j) {
#pragma unroll 2
        for (int ks = 0; ks < 10; ++ks) {
            int c = (j * 10 + ks) * 4 + kg;
            short8 a[4], bb[4];
#pragma unroll
            for (int m = 0; m < 4; ++m) {
                int row = m * 16 + rl + j;
                a[m] = *(const short8*)(ldsc + row * SE_PITCH +
                                        ((((ks << 2) + kg) ^ (row & 7)) << 4));
            }
#pragma unroll
            for (int nn = 0; nn < 4; ++nn)
                bb[nn] = Wb2[(c * 16 + (w * 4 + nn)) * 16 + rl];
#pragma unroll
            for (int m = 0; m < 4; ++m)
#pragma unroll
                for (int nn = 0; nn < 4; ++nn)
                    cacc[m][nn] = MFMA(a[m], bb[nn], cacc[m][nn]);
        }
    }
    __syncthreads();   // all s_emb reads done; s_conv may overwrite

    // ---- Phase 6: write s_conv bf16 into (former s_emb) region
#pragma unroll
    for (int m = 0; m < 4; ++m)
#pragma unroll
        for (int nn = 0; nn < 4; ++nn) {
            int f = (w * 4 + nn) * 16 + rl;
#pragma unroll
            for (int reg = 0; reg < 4; ++reg) {
                int tr = m * 16 + kg * 4 + reg;
                *(unsigned short*)(ldsc + tr * SC_PITCH +
                                   (((f >> 3) ^ (tr & 7)) << 4) + ((f & 7) << 1)) =
                    f2bf(cacc[m][nn][reg]);
            }
        }
    __syncthreads();

    // ---- Phase 7: sim_sens MFMA (K=256) + scnorm via Gram diag
    {
        f32x4 sacc0 = (f32x4){0.f, 0.f, 0.f, 0.f};
        f32x4 sacc1 = (f32x4){0.f, 0.f, 0.f, 0.f};
        f32x4 nB = (f32x4){0.f, 0.f, 0.f, 0.f};
        const short8* qc = qcf + (size_t)(b * 64) * 16;
#pragma unroll 2
        for (int ks = 0; ks < 8; ++ks) {
            int c = ks * 4 + kg;
            short8 bB = *(const short8*)(ldsc + t * SC_PITCH + ((c ^ t7) << 4));
            short8 a0 = qc[c * 16 + rl];
            short8 a1 = qc[(32 + c) * 16 + rl];
            sacc0 = MFMA(a0, bB, sacc0);
            sacc1 = MFMA(a1, bB, sacc1);
            nB = MFMA(bB, bB, nB);
        }
        if (kg == (rl >> 2)) scnorm[t] = sqrtf(nB[rl & 3]);
        __syncthreads();

        // ---- Phase 8: scale + write sim_sens (reuse SIM buffer)
        float inv_t = 1.f / scnorm[t];
#pragma unroll
        for (int reg = 0; reg < 4; ++reg) {
            int q0 = kg * 4 + reg;
            *(float*)(ldsc + SIM_OFF + (q0 * SIM_PITCH + t) * 4) =
                sacc0[reg] / qcn_s[q0] * inv_t;
            int q1 = 16 + kg * 4 + reg;
            *(float*)(ldsc + SIM_OFF + (q1 * SIM_PITCH + t) * 4) =
                sacc1[reg] / qcn_s[q1] * inv_t;
        }
    }
    __syncthreads();

    // ---- Phase 9: pool sens + oh + head (wave w owns q = 8w..8w+7)
    {
        float lw0 = lin_w[0], lw1 = lin_w[1], lw2 = lin_w[2];
        float lw3 = lin_w[3], lw4 = lin_w[4], lw5 = lin_w[5];
        float lb = lin_b[0];
        int q0 = w << 3;
        float sv[8];
#pragma unroll
        for (int qi = 0; qi < 8; ++qi)
            sv[qi] = *(float*)(ldsc + SIM_OFF + ((q0 + qi) * SIM_PITCH + lane) * 4);
        float mxs[8], mns[8], mxo[8], mno[8];
        top5_pool4(sv[0], sv[1], sv[2], sv[3], lane, mxs, mns);
        top5_pool4(sv[4], sv[5], sv[6], sv[7], lane, mxs + 4, mns + 4);
        top5_pool4(oh[0], oh[1], oh[2], oh[3], lane, mxo, mno);
        top5_pool4(oh[4], oh[5], oh[6], oh[7], lane, mxo + 4, mno + 4);
        float psum = 0.f;
#pragma unroll
        for (int qi = 0; qi < 8; ++qi) {
            float f0 = fpool[q0 + qi][0], f1 = fpool[q0 + qi][1];
            float z = f0 * lw0 + f1 * lw1 + mxs[qi] * lw2 + mns[qi] * lw3 +
                      mxo[qi] * lw4 + mno[qi] * lw5 + lb;
            psum += 1.f / (1.f + expf(-z));
        }
        if (lane == 0) wq[w] = psum;
    }
    __syncthreads();
    if (tid == 0) {
        float sent = (wq[0] + wq[1] + wq[2] + wq[3]) * (1.f / 32.f);
        __hip_atomic_store(&sent_ws[bs], sent, __ATOMIC_RELEASE, __HIP_MEMORY_SCOPE_AGENT);
        d_out[1 + bs] = sent;
        unsigned old = atomicAdd(done_ctr, 1u);
        lastflag = (old == (unsigned)(NB * NS - 1)) ? 1 : 0;
    }
    __syncthreads();

    // ---- last block computes losses + doc_emit
    if (lastflag) {
        float acc_l = 0.f;
        for (int i = tid; i < NB * NS; i += 256) {
            float p = __hip_atomic_load(&sent_ws[i], __ATOMIC_ACQUIRE, __HIP_MEMORY_SCOPE_AGENT);
            float tt2 = (float)tsent[i];
            acc_l += tt2 * logf(p) + (1.f - tt2) * logf(1.f - p);
        }
        acc_l = wave_reduce_sum(acc_l);
        if ((tid & 63) == 0) red2[tid >> 6] = acc_l;
        if (tid < NB) {
            float m = -3.4e38f;
            for (int s = 0; s < NS; ++s)
                m = fmaxf(m, __hip_atomic_load(&sent_ws[tid * NS + s], __ATOMIC_ACQUIRE,
                                               __HIP_MEMORY_SCOPE_AGENT));
            d_out[1 + NB * NS + tid] = m;
            float tt2 = (float)tdoc[tid];
            dred[tid] = tt2 * logf(m) + (1.f - tt2) * logf(1.f - m);
        }
        __syncthreads();
        if (tid == 0) {
            float sal = -(red2[0] + red2[1] + red2[2] + red2[3]) / (float)(NB * NS);
            float dsum = 0.f;
            for (int i = 0; i < NB; ++i) dsum += dred[i];
            float dal = -dsum / (float)NB;
            d_out[0] = 0.5f * (sal + dal);
        }
    }
}

extern "C" void kernel_launch(void* const* d_in, const int* in_sizes, int n_in,
                              void* d_out, int out_size, void* d_ws, size_t ws_size,
                              hipStream_t stream) {
    const int* sentences = (const int*)d_in[0];
    const int* question = (const int*)d_in[1];
    const int* tsent = (const int*)d_in[2];
    const int* tdoc = (const int*)d_in[3];
    const float* sim_oh = (const float*)d_in[4];
    const float* embeds = (const float*)d_in[5];
    const float* conv_w = (const float*)d_in[6];
    const float* lin_w = (const float*)d_in[7];
    const float* lin_b = (const float*)d_in[8];
    float* out = (float*)d_out;

    char* wsc = (char*)d_ws;
    short8* Wb2            = (short8*)(wsc);                     // 491520 B
    unsigned short* qe_old = (unsigned short*)(wsc + 491520);    // 368640 B
    short8* qef            = (short8*)(wsc + 860160);            // 327680 B
    short8* qcf            = (short8*)(wsc + 1187840);           // 262144 B
    float* q_norm          = (float*)(wsc + 1449984);            // 2048 B
    float* qcssq           = (float*)(wsc + 1452032);            // 2048 B
    float* sent_ws         = (float*)(wsc + 1454080);            // 3072 B
    unsigned int* done_ctr = (unsigned int*)(wsc + 1457152);     // 16 B

    hipFuncSetAttribute(reinterpret_cast<const void*>(fused8_kernel),
                        hipFuncAttributeMaxDynamicSharedMemorySize, DYN_LDS);

    prep_kernel<<<264, 256, 0, stream>>>(conv_w, question, embeds,
                                         Wb2, qe_old, qef, q_norm, qcssq, done_ctr);
    qconv_mfma_kernel<<<NB * 4, 256, 0, stream>>>(qe_old, Wb2, qcf, qcssq);
    fused8_kernel<<<NB * NS, 256, DYN_LDS, stream>>>(
        sentences, question, sim_oh, embeds, Wb2, qef, qcf, q_norm, qcssq,
        lin_w, lin_b, tsent, tdoc, done_ctr, sent_ws, out);
}

// Round 13
// 113.200 us; speedup vs baseline: 1.4356x; 1.1152x over previous
//
#include <hip/hip_runtime.h>
#include <math.h>

#define NB 16
#define NS 48
#define NL 64
#define NQ 32
#define NE 300
#define NF 256
#define KP 320            // padded K for embeddings (bf16)
#define QROWS 36          // qe rows per b (32 + zero pad for taps)

typedef __attribute__((ext_vector_type(8))) short short8;
typedef __attribute__((ext_vector_type(4))) float f32x4;

#define MFMA(a,b,c) __builtin_amdgcn_mfma_f32_16x16x32_bf16((a),(b),(c),0,0,0)

__device__ __forceinline__ unsigned short f2bf(float f) {
    unsigned u = __float_as_uint(f);
    u += 0x7fff + ((u >> 16) & 1);           // RNE
    return (unsigned short)(u >> 16);
}

// dynamic-LDS byte offsets (s_conv region overlays s_emb region)
#define SE_PITCH 640                        // 320 bf16 per row, 66 rows
#define SC_PITCH 512                        // 256 bf16 per row, 64 rows (overlay)
#define SIM_OFF (66 * 640)                  // 42240
#define SIM_PITCH 66                        // floats per q-row
#define DYN_LDS (SIM_OFF + NQ * SIM_PITCH * 4)   // 50688 bytes

__device__ __forceinline__ float wave_reduce_sum(float v) {
#pragma unroll
    for (int off = 32; off; off >>= 1) v += __shfl_xor(v, off, 64);
    return v;
}

// top-5 pooling over 64 values for 8 q's simultaneously.
// Lane = g*8 + j: group g owns one q; lane holds 8 values v[0..7] (t = j*8..j*8+7).
// Result (max, mean-of-top5) is uniform across each 8-lane group.
__device__ __forceinline__ void top5_pool_g8(const float* v, int lane,
                                             float& mx, float& mn) {
    const float NEG = -3.4e38f;
    float s0 = NEG, s1 = NEG, s2 = NEG, s3 = NEG, s4 = NEG;
#pragma unroll
    for (int e = 0; e < 8; ++e) {
        float x = v[e], t;
        t = fmaxf(s0, x); x = fminf(s0, x); s0 = t;
        t = fmaxf(s1, x); x = fminf(s1, x); s1 = t;
        t = fmaxf(s2, x); x = fminf(s2, x); s2 = t;
        t = fmaxf(s3, x); x = fminf(s3, x); s3 = t;
        t = fmaxf(s4, x); x = fminf(s4, x); s4 = t;
    }
    int gb = lane & 56;          // group base bit offset in ballot
    int j = lane & 7;
    float sum = 0.f, first = 0.f;
#pragma unroll
    for (int i = 0; i < 5; ++i) {
        float m = s0;
        m = fmaxf(m, __shfl_xor(m, 1, 64));
        m = fmaxf(m, __shfl_xor(m, 2, 64));
        m = fmaxf(m, __shfl_xor(m, 4, 64));
        if (i == 0) first = m;
        sum += m;
        unsigned long long bal = __ballot(s0 == m);
        int leader = __ffsll((unsigned long long)((bal >> gb) & 0xffull)) - 1;
        if (j == leader) { s0 = s1; s1 = s2; s2 = s3; s3 = s4; s4 = NEG; }
    }
    mx = first;
    mn = sum * 0.2f;
}

// ---------- prep: blocks 0..119 pack conv_w -> Wb2 fragments (+zero qcssq/ctr);
//            blocks 120..263 gather q_emb (4 rows each) -> qe taps + qef fragments + q_norm
__global__ __launch_bounds__(256) void prep_kernel(
        const float* __restrict__ conv_w, const int* __restrict__ question,
        const float* __restrict__ embeds,
        short8* __restrict__ Wb2, unsigned short* __restrict__ qe,
        short8* __restrict__ qef, float* __restrict__ q_norm,
        float* __restrict__ qcssq, unsigned int* __restrict__ done_ctr) {
    int blk = blockIdx.x;
    int tid = threadIdx.x;
    if (blk < 120) {
        if (blk == 0 && tid == 0) done_ctr[0] = 0u;
        int i = blk * 256 + tid;
        if (i < NB * NQ) qcssq[i] = 0.f;
        int rl = i & 15;
        int ftile = (i >> 4) & 15;
        int c = i >> 8;
        int kg = c & 3, rest = c >> 2;
        int ks = rest % 10, j = rest / 10;
        int f = ftile * 16 + rl;
        int k0 = ks * 32 + kg * 8;
        const float* src = conv_w + (size_t)(f * 3 + j) * NE;
        short8 h;
#pragma unroll
        for (int e = 0; e < 8; ++e) {
            int k = k0 + e;
            h[e] = (short)((k < NE) ? f2bf(src[k]) : (unsigned short)0);
        }
        Wb2[i] = h;
    } else {
        int row = (blk - 120) * 4 + (tid >> 6);  // 0..575 = b*36 + r
        int b = row / QROWS, r = row % QROWS;
        int l = tid & 63;
        unsigned short* dst = qe + (size_t)row * KP;
        if (r < NQ) {
            int tok = question[b * NQ + r];
            const float4* rp = (const float4*)(embeds + (size_t)tok * NE);
            short8 h = {0, 0, 0, 0, 0, 0, 0, 0};
            float ss = 0.f;
            if (l < 38) {
                float4 v0 = rp[2 * l];
                ss += v0.x * v0.x + v0.y * v0.y + v0.z * v0.z + v0.w * v0.w;
                h[0] = (short)f2bf(v0.x); h[1] = (short)f2bf(v0.y);
                h[2] = (short)f2bf(v0.z); h[3] = (short)f2bf(v0.w);
                if (2 * l + 1 < 75) {
                    float4 v1 = rp[2 * l + 1];
                    ss += v1.x * v1.x + v1.y * v1.y + v1.z * v1.z + v1.w * v1.w;
                    h[4] = (short)f2bf(v1.x); h[5] = (short)f2bf(v1.y);
                    h[6] = (short)f2bf(v1.z); h[7] = (short)f2bf(v1.w);
                }
            }
            if (l < 40) {
                *(short8*)(dst + 8 * l) = h;
                qef[((size_t)(b * 2 + (r >> 4)) * 40 + l) * 16 + (r & 15)] = h;
            }
            ss = wave_reduce_sum(ss);
            if (l == 0) q_norm[b * NQ + r] = sqrtf(ss);
        } else {
            if (l < 40) {
                short8 z = {0, 0, 0, 0, 0, 0, 0, 0};
                *(short8*)(dst + 8 * l) = z;
            }
        }
    }
}

// ---------- q_conv via MFMA -> A-fragments + partial qc ssq (certified r9)
__global__ __launch_bounds__(256) void qconv_mfma_kernel(
        const unsigned short* __restrict__ qe, const short8* __restrict__ Wb2,
        short8* __restrict__ qcf, float* __restrict__ qcssq) {
    __shared__ unsigned short tile[NQ][72];
    int b = blockIdx.x >> 2, fq = blockIdx.x & 3;
    int tid = threadIdx.x, lane = tid & 63, w = tid >> 6;
    int rl = lane & 15, kg = lane >> 4;
    int ftile = fq * 4 + w;
    f32x4 acc0 = (f32x4){0.f, 0.f, 0.f, 0.f};
    f32x4 acc1 = (f32x4){0.f, 0.f, 0.f, 0.f};
    for (int j = 0; j < 3; ++j) {
#pragma unroll 2
        for (int ks = 0; ks < 10; ++ks) {
            int k = ks * 32 + kg * 8;
            int c = (j * 10 + ks) * 4 + kg;
            short8 a0 = *(const short8*)(qe + ((size_t)(b * QROWS) + rl + j) * KP + k);
            short8 a1 = *(const short8*)(qe + ((size_t)(b * QROWS) + 16 + rl + j) * KP + k);
            short8 bb = Wb2[(c * 16 + ftile) * 16 + rl];
            acc0 = MFMA(a0, bb, acc0);
            acc1 = MFMA(a1, bb, acc1);
        }
    }
    int fl = w * 16 + rl;
#pragma unroll
    for (int reg = 0; reg < 4; ++reg) {
        tile[kg * 4 + reg][fl] = f2bf(acc0[reg]);
        tile[16 + kg * 4 + reg][fl] = f2bf(acc1[reg]);
    }
    __syncthreads();
    {
        int mh = tid >> 7, c_local = (tid >> 4) & 7, rl2 = tid & 15;
        short8 h = *(const short8*)(&tile[mh * 16 + rl2][c_local * 8]);
        qcf[((size_t)(b * 2 + mh) * 32 + 8 * fq + c_local) * 16 + rl2] = h;
    }
    {
        int qq = tid >> 3, fgrp = tid & 7;
        short8 h = *(const short8*)(&tile[qq][fgrp * 8]);
        float ss = 0.f;
#pragma unroll
        for (int e = 0; e < 8; ++e) {
            float v = __uint_as_float(((unsigned)(unsigned short)h[e]) << 16);
            ss += v * v;
        }
        ss += __shfl_xor(ss, 1, 64);
        ss += __shfl_xor(ss, 2, 64);
        ss += __shfl_xor(ss, 4, 64);
        if (fgrp == 0) atomicAdd(&qcssq[b * NQ + qq], ss);
    }
}

// ---------- fused per-(b,s), 4 waves (r12 structure + group-of-8 pools)
extern __shared__ char ldsc[];
__global__ __launch_bounds__(256, 3) void fused9_kernel(
    const int* __restrict__ sentences, const int* __restrict__ question,
    const float* __restrict__ sim_oh, const float* __restrict__ embeds,
    const short8* __restrict__ Wb2,
    const short8* __restrict__ qef, const short8* __restrict__ qcf,
    const float* __restrict__ q_norm, const float* __restrict__ qcssq,
    const float* __restrict__ lin_w, const float* __restrict__ lin_b,
    const int* __restrict__ tsent, const int* __restrict__ tdoc,
    unsigned int* __restrict__ done_ctr,
    float* __restrict__ sent_ws, float* __restrict__ d_out)
{
    __shared__ int toks[NL];
    __shared__ float smaskf[NL], snorm[NL], scnorm[NL];
    __shared__ float qn_s[NQ], qcn_s[NQ], qmf_s[NQ];
    __shared__ float wq[4];
    __shared__ int lastflag;
    __shared__ float red2[4];
    __shared__ float dred[NB];

    int tid = threadIdx.x, lane = tid & 63, w = tid >> 6;
    int rl = lane & 15, kg = lane >> 4;
    int bs = blockIdx.x, b = bs / NS;
    int t = (w << 4) + rl, t7 = t & 7;
    int pg = lane >> 3, pj = lane & 7;      // pooling group / chunk

    // ---- Phase 0: prefetch oh in group-of-8 layout (q = 8w+pg, t = 8pj..8pj+7)
    float ohv[8];
    {
        const float* ohp = sim_oh + ((size_t)bs * NQ + (w << 3) + pg) * NL + (pj << 3);
        float4 o0 = *(const float4*)(ohp);
        float4 o1 = *(const float4*)(ohp + 4);
        ohv[0] = o0.x; ohv[1] = o0.y; ohv[2] = o0.z; ohv[3] = o0.w;
        ohv[4] = o1.x; ohv[5] = o1.y; ohv[6] = o1.z; ohv[7] = o1.w;
    }

    // ---- header loads
    if (tid < NL) {
        int tk = sentences[(size_t)bs * NL + tid];
        toks[tid] = tk;
        smaskf[tid] = (tk > 1) ? 1.f : 0.f;
    } else if (tid < NL + NQ) {
        int q = tid - NL;
        qn_s[q] = q_norm[b * NQ + q];
    } else if (tid < NL + 2 * NQ) {
        int q = tid - NL - NQ;
        qcn_s[q] = sqrtf(qcssq[b * NQ + q]);
    } else if (tid < NL + 3 * NQ) {
        int q = tid - NL - 2 * NQ;
        qmf_s[q] = (question[b * NQ + q] > 1) ? 1.f : 0.f;
    }
    __syncthreads();

    // ---- Phase 1: gather s_emb -> LDS bf16 (swizzled), unroll 4 for load ILP
#pragma unroll 4
    for (int i = 0; i < 16; ++i) {
        int r = (i << 2) + w;
        char* rowbase = ldsc + r * SE_PITCH;
        int m7 = r & 7;
        const float4* rp = (const float4*)(embeds + (size_t)toks[r] * NE);
        {
            float4 v = rp[lane];
            ushort4 h = {f2bf(v.x), f2bf(v.y), f2bf(v.z), f2bf(v.w)};
            *(ushort4*)(rowbase + (((lane >> 1) ^ m7) << 4) + ((lane & 1) << 3)) = h;
        }
        if (lane < 11) {
            float4 v = rp[64 + lane];
            ushort4 h = {f2bf(v.x), f2bf(v.y), f2bf(v.z), f2bf(v.w)};
            int g = 64 + lane;
            *(ushort4*)(rowbase + (((g >> 1) ^ m7) << 4) + ((g & 1) << 3)) = h;
        }
        if (lane < 5) {
            int pk = 37 + ((lane + 1) >> 1);
            int sub = ((lane + 1) & 1) << 3;
            *(unsigned long long*)(rowbase + ((pk ^ m7) << 4) + sub) = 0ull;
        }
    }
    if (w < 2) {
        int r = 64 + w;
        if (lane < 40) {
            uint4 z = {0, 0, 0, 0};
            *(uint4*)(ldsc + r * SE_PITCH + (lane << 4)) = z;
        }
    }
    __syncthreads();

    // ---- Phase 2: sim_ins MFMA (wave w = t-tile, M=32 q) + snorm via Gram diag
    {
        f32x4 iacc0 = (f32x4){0.f, 0.f, 0.f, 0.f};
        f32x4 iacc1 = (f32x4){0.f, 0.f, 0.f, 0.f};
        f32x4 nB = (f32x4){0.f, 0.f, 0.f, 0.f};
        const short8* qf = qef + (size_t)(b * 80) * 16;
#pragma unroll 2
        for (int ks = 0; ks < 10; ++ks) {
            int c = ks * 4 + kg;
            short8 bB = *(const short8*)(ldsc + t * SE_PITCH + ((c ^ t7) << 4));
            short8 a0 = qf[c * 16 + rl];
            short8 a1 = qf[(40 + c) * 16 + rl];
            iacc0 = MFMA(a0, bB, iacc0);
            iacc1 = MFMA(a1, bB, iacc1);
            nB = MFMA(bB, bB, nB);
        }
        if (kg == (rl >> 2)) snorm[t] = sqrtf(nB[rl & 3]);
        __syncthreads();

        // ---- Phase 3: scale + write sim_ins
        float inv_t = smaskf[t] / snorm[t];
#pragma unroll
        for (int reg = 0; reg < 4; ++reg) {
            int q0 = kg * 4 + reg;
            float s0 = iacc0[reg] / qn_s[q0] * inv_t * qmf_s[q0];
            *(float*)(ldsc + SIM_OFF + (q0 * SIM_PITCH + t) * 4) = s0;
            int q1 = 16 + kg * 4 + reg;
            float s1 = iacc1[reg] / qn_s[q1] * inv_t * qmf_s[q1];
            *(float*)(ldsc + SIM_OFF + (q1 * SIM_PITCH + t) * 4) = s1;
        }
    }
    __syncthreads();

    // ---- Phase 4: pool sim_ins (wave w owns q = 8w..8w+7), one group-of-8 batch.
    //      Results stay in registers until phase 9 (uniform in each 8-lane group).
    float f_i0, f_i1;
    {
        const float* basep = (const float*)(ldsc + SIM_OFF) +
                             ((w << 3) + pg) * SIM_PITCH + (pj << 3);
        float v[8];
#pragma unroll
        for (int e = 0; e < 8; e += 2) {
            float2 p = *(const float2*)(basep + e);
            v[e] = p.x; v[e + 1] = p.y;
        }
        top5_pool_g8(v, lane, f_i0, f_i1);
    }

    // ---- Phase 5: conv MFMA. wave w owns f-tiles 4w..4w+3, all 4 t-tiles.
    f32x4 cacc[4][4];
#pragma unroll
    for (int m = 0; m < 4; ++m)
#pragma unroll
        for (int nn = 0; nn < 4; ++nn) cacc[m][nn] = (f32x4){0.f, 0.f, 0.f, 0.f};
    for (int j = 0; j < 3; ++j) {
#pragma unroll 2
        for (int ks = 0; ks < 10; ++ks) {
            int c = (j * 10 + ks) * 4 + kg;
            short8 a[4], bb[4];
#pragma unroll
            for (int m = 0; m < 4; ++m) {
                int row = m * 16 + rl + j;
                a[m] = *(const short8*)(ldsc + row * SE_PITCH +
                                        ((((ks << 2) + kg) ^ (row & 7)) << 4));
            }
#pragma unroll
            for (int nn = 0; nn < 4; ++nn)
                bb[nn] = Wb2[(c * 16 + (w * 4 + nn)) * 16 + rl];
#pragma unroll
            for (int m = 0; m < 4; ++m)
#pragma unroll
                for (int nn = 0; nn < 4; ++nn)
                    cacc[m][nn] = MFMA(a[m], bb[nn], cacc[m][nn]);
        }
    }
    __syncthreads();   // all s_emb reads done; s_conv may overwrite

    // ---- Phase 6: write s_conv bf16 into (former s_emb) region
#pragma unroll
    for (int m = 0; m < 4; ++m)
#pragma unroll
        for (int nn = 0; nn < 4; ++nn) {
            int f = (w * 4 + nn) * 16 + rl;
#pragma unroll
            for (int reg = 0; reg < 4; ++reg) {
                int tr = m * 16 + kg * 4 + reg;
                *(unsigned short*)(ldsc + tr * SC_PITCH +
                                   (((f >> 3) ^ (tr & 7)) << 4) + ((f & 7) << 1)) =
                    f2bf(cacc[m][nn][reg]);
            }
        }
    __syncthreads();

    // ---- Phase 7: sim_sens MFMA (K=256) + scnorm via Gram diag
    {
        f32x4 sacc0 = (f32x4){0.f, 0.f, 0.f, 0.f};
        f32x4 sacc1 = (f32x4){0.f, 0.f, 0.f, 0.f};
        f32x4 nB = (f32x4){0.f, 0.f, 0.f, 0.f};
        const short8* qc = qcf + (size_t)(b * 64) * 16;
#pragma unroll 2
        for (int ks = 0; ks < 8; ++ks) {
            int c = ks * 4 + kg;
            short8 bB = *(const short8*)(ldsc + t * SC_PITCH + ((c ^ t7) << 4));
            short8 a0 = qc[c * 16 + rl];
            short8 a1 = qc[(32 + c) * 16 + rl];
            sacc0 = MFMA(a0, bB, sacc0);
            sacc1 = MFMA(a1, bB, sacc1);
            nB = MFMA(bB, bB, nB);
        }
        if (kg == (rl >> 2)) scnorm[t] = sqrtf(nB[rl & 3]);
        __syncthreads();

        // ---- Phase 8: scale + write sim_sens (reuse SIM buffer)
        float inv_t = 1.f / scnorm[t];
#pragma unroll
        for (int reg = 0; reg < 4; ++reg) {
            int q0 = kg * 4 + reg;
            *(float*)(ldsc + SIM_OFF + (q0 * SIM_PITCH + t) * 4) =
                sacc0[reg] / qcn_s[q0] * inv_t;
            int q1 = 16 + kg * 4 + reg;
            *(float*)(ldsc + SIM_OFF + (q1 * SIM_PITCH + t) * 4) =
                sacc1[reg] / qcn_s[q1] * inv_t;
        }
    }
    __syncthreads();

    // ---- Phase 9: pool sens + oh (group-of-8) + head
    {
        float lw0 = lin_w[0], lw1 = lin_w[1], lw2 = lin_w[2];
        float lw3 = lin_w[3], lw4 = lin_w[4], lw5 = lin_w[5];
        float lb = lin_b[0];
        const float* basep = (const float*)(ldsc + SIM_OFF) +
                             ((w << 3) + pg) * SIM_PITCH + (pj << 3);
        float sv[8];
#pragma unroll
        for (int e = 0; e < 8; e += 2) {
            float2 p = *(const float2*)(basep + e);
            sv[e] = p.x; sv[e + 1] = p.y;
        }
        float mxs, mns, mxo, mno;
        top5_pool_g8(sv, lane, mxs, mns);
        top5_pool_g8(ohv, lane, mxo, mno);
        float z = f_i0 * lw0 + f_i1 * lw1 + mxs * lw2 + mns * lw3 +
                  mxo * lw4 + mno * lw5 + lb;
        float p = 1.f / (1.f + expf(-z));
        float contrib = (pj == 0) ? p : 0.f;
        contrib = wave_reduce_sum(contrib);
        if (lane == 0) wq[w] = contrib;
    }
    __syncthreads();
    if (tid == 0) {
        float sent = (wq[0] + wq[1] + wq[2] + wq[3]) * (1.f / 32.f);
        __hip_atomic_store(&sent_ws[bs], sent, __ATOMIC_RELEASE, __HIP_MEMORY_SCOPE_AGENT);
        d_out[1 + bs] = sent;
        unsigned old = atomicAdd(done_ctr, 1u);
        lastflag = (old == (unsigned)(NB * NS - 1)) ? 1 : 0;
    }
    __syncthreads();

    // ---- last block computes losses + doc_emit
    if (lastflag) {
        float acc_l = 0.f;
        for (int i = tid; i < NB * NS; i += 256) {
            float p = __hip_atomic_load(&sent_ws[i], __ATOMIC_ACQUIRE, __HIP_MEMORY_SCOPE_AGENT);
            float tt2 = (float)tsent[i];
            acc_l += tt2 * logf(p) + (1.f - tt2) * logf(1.f - p);
        }
        acc_l = wave_reduce_sum(acc_l);
        if ((tid & 63) == 0) red2[tid >> 6] = acc_l;
        if (tid < NB) {
            float m = -3.4e38f;
            for (int s = 0; s < NS; ++s)
                m = fmaxf(m, __hip_atomic_load(&sent_ws[tid * NS + s], __ATOMIC_ACQUIRE,
                                               __HIP_MEMORY_SCOPE_AGENT));
            d_out[1 + NB * NS + tid] = m;
            float tt2 = (float)tdoc[tid];
            dred[tid] = tt2 * logf(m) + (1.f - tt2) * logf(1.f - m);
        }
        __syncthreads();
        if (tid == 0) {
            float sal = -(red2[0] + red2[1] + red2[2] + red2[3]) / (float)(NB * NS);
            float dsum = 0.f;
            for (int i = 0; i < NB; ++i) dsum += dred[i];
            float dal = -dsum / (float)NB;
            d_out[0] = 0.5f * (sal + dal);
        }
    }
}

extern "C" void kernel_launch(void* const* d_in, const int* in_sizes, int n_in,
                              void* d_out, int out_size, void* d_ws, size_t ws_size,
                              hipStream_t stream) {
    const int* sentences = (const int*)d_in[0];
    const int* question = (const int*)d_in[1];
    const int* tsent = (const int*)d_in[2];
    const int* tdoc = (const int*)d_in[3];
    const float* sim_oh = (const float*)d_in[4];
    const float* embeds = (const float*)d_in[5];
    const float* conv_w = (const float*)d_in[6];
    const float* lin_w = (const float*)d_in[7];
    const float* lin_b = (const float*)d_in[8];
    float* out = (float*)d_out;

    char* wsc = (char*)d_ws;
    short8* Wb2            = (short8*)(wsc);                     // 491520 B
    unsigned short* qe_old = (unsigned short*)(wsc + 491520);    // 368640 B
    short8* qef            = (short8*)(wsc + 860160);            // 327680 B
    short8* qcf            = (short8*)(wsc + 1187840);           // 262144 B
    float* q_norm          = (float*)(wsc + 1449984);            // 2048 B
    float* qcssq           = (float*)(wsc + 1452032);            // 2048 B
    float* sent_ws         = (float*)(wsc + 1454080);            // 3072 B
    unsigned int* done_ctr = (unsigned int*)(wsc + 1457152);     // 16 B

    hipFuncSetAttribute(reinterpret_cast<const void*>(fused9_kernel),
                        hipFuncAttributeMaxDynamicSharedMemorySize, DYN_LDS);

    prep_kernel<<<264, 256, 0, stream>>>(conv_w, question, embeds,
                                         Wb2, qe_old, qef, q_norm, qcssq, done_ctr);
    qconv_mfma_kernel<<<NB * 4, 256, 0, stream>>>(qe_old, Wb2, qcf, qcssq);
    fused9_kernel<<<NB * NS, 256, DYN_LDS, stream>>>(
        sentences, question, sim_oh, embeds, Wb2, qef, qcf, q_norm, qcssq,
        lin_w, lin_b, tsent, tdoc, done_ctr, sent_ws, out);
}